// Round 3
// baseline (196.384 us; speedup 1.0000x reference)
//
#include <hip/hip_runtime.h>

#define BB 4
#define H 320
#define W 768
#define P (H*W)           // 245760
#define NPIX (BB*P)       // 983040

#define TX 32
#define TY 8
#define TW (TX+6)  // 38
#define TH (TY+6)  // 14
#define HALO (TW*TH)      // 532
#define NBX (W/TX)        // 24
#define NBY (H/TY)        // 40

// ---- float2 helpers (encourage v_pk_* packed fp32) ----
__device__ __forceinline__ float2 f2(float x, float y) { return make_float2(x, y); }
__device__ __forceinline__ float2 operator+(float2 a, float2 b) { return f2(a.x + b.x, a.y + b.y); }
__device__ __forceinline__ float2 operator-(float2 a, float2 b) { return f2(a.x - b.x, a.y - b.y); }
__device__ __forceinline__ float2 operator*(float2 a, float2 b) { return f2(a.x * b.x, a.y * b.y); }
__device__ __forceinline__ float2 pk_fma(float2 a, float2 b, float2 c) {
    return f2(fmaf(a.x, b.x, c.x), fmaf(a.y, b.y, c.y));
}
__device__ __forceinline__ float2 pk_fma_s(float s, float2 b, float2 c) {
    return f2(fmaf(s, b.x, c.x), fmaf(s, b.y, c.y));
}
__device__ __forceinline__ float2 pk_add_s(float2 a, float s) { return f2(a.x + s, a.y + s); }

// ---------------- gray kernel (float4, + zero out) ----------------
__global__ void gray_kernel(const float* __restrict__ former,
                            const float* __restrict__ latter,
                            float* __restrict__ gf, float* __restrict__ gl,
                            float* __restrict__ out) {
    int idx = blockIdx.x * blockDim.x + threadIdx.x;
    if (idx == 0) { out[0] = 0.f; out[1] = 0.f; }
    if (idx >= NPIX / 4) return;
    int idx4 = idx * 4;
    int b = idx4 / P;
    int r = idx4 - b * P;
    const float* f = former + (size_t)b * 3 * P + r;
    const float* l = latter + (size_t)b * 3 * P + r;
    float4 fr = *(const float4*)f;
    float4 fg = *(const float4*)(f + P);
    float4 fb = *(const float4*)(f + 2 * P);
    float4 lr = *(const float4*)l;
    float4 lg = *(const float4*)(l + P);
    float4 lb = *(const float4*)(l + 2 * P);
    float4 og, ol;
    og.x = (0.299f * fr.x + 0.587f * fg.x + 0.114f * fb.x) * 255.f;
    og.y = (0.299f * fr.y + 0.587f * fg.y + 0.114f * fb.y) * 255.f;
    og.z = (0.299f * fr.z + 0.587f * fg.z + 0.114f * fb.z) * 255.f;
    og.w = (0.299f * fr.w + 0.587f * fg.w + 0.114f * fb.w) * 255.f;
    ol.x = (0.299f * lr.x + 0.587f * lg.x + 0.114f * lb.x) * 255.f;
    ol.y = (0.299f * lr.y + 0.587f * lg.y + 0.114f * lb.y) * 255.f;
    ol.z = (0.299f * lr.z + 0.587f * lg.z + 0.114f * lb.z) * 255.f;
    ol.w = (0.299f * lr.w + 0.587f * lg.w + 0.114f * lb.w) * 255.f;
    *(float4*)(gf + idx4) = og;
    *(float4*)(gl + idx4) = ol;
}

__device__ __forceinline__ float bilinear(const float* __restrict__ img, float fx, float fy) {
    float x0 = floorf(fx), y0 = floorf(fy);
    float wx = fx - x0, wy = fy - y0;
    float x0c = fminf(fmaxf(x0,       0.f), (float)(W - 1));
    float x1c = fminf(fmaxf(x0 + 1.f, 0.f), (float)(W - 1));
    float y0c = fminf(fmaxf(y0,       0.f), (float)(H - 1));
    float y1c = fminf(fmaxf(y0 + 1.f, 0.f), (float)(H - 1));
    int x0i = (int)x0c, x1i = (int)x1c, y0i = (int)y0c, y1i = (int)y1c;
    float Ia = img[y0i * W + x0i], Ib = img[y0i * W + x1i];
    float Ic = img[y1i * W + x0i], Id = img[y1i * W + x1i];
    float omx = 1.f - wx, omy = 1.f - wy;
    return Ia * omx * omy + Ib * wx * omy + Ic * omx * wy + Id * wx * wy;
}

// ---------------- fused warp + census + distance + charbonnier ----------------
__global__ __launch_bounds__(256)
void fused_kernel(const float* __restrict__ gf, const float* __restrict__ gl,
                  const float* __restrict__ flow1, const float* __restrict__ flow2,
                  const float* __restrict__ fw_mask, const float* __restrict__ bw_mask,
                  float* __restrict__ out) {
    __shared__ float2 sAC[HALO];  // {former-gray, latter-gray}
    __shared__ float2 sBD[HALO];  // {warp(latter,flow1), warp(former,flow2)}
    const int b   = blockIdx.z;
    const int tx0 = blockIdx.x * TX;
    const int ty0 = blockIdx.y * TY;
    const int tid = threadIdx.x;

    const float* pGF = gf + (size_t)b * P;
    const float* pGL = gl + (size_t)b * P;
    const float* pF1 = flow1 + (size_t)b * 2 * P;
    const float* pF2 = flow2 + (size_t)b * 2 * P;

    for (int i = tid; i < HALO; i += 256) {
        int ly = i / TW, lx = i - ly * TW;
        int gx = min(max(tx0 - 3 + lx, 0), W - 1);
        int gy = min(max(ty0 - 3 + ly, 0), H - 1);
        int o = gy * W + gx;
        sAC[i] = f2(pGF[o], pGL[o]);
        float u1 = pF1[o], v1 = pF1[P + o];
        float u2 = pF2[o], v2 = pF2[P + o];
        sBD[i] = f2(bilinear(pGL, (float)gx + u1, (float)gy + v1),
                    bilinear(pGF, (float)gx + u2, (float)gy + v2));
    }
    __syncthreads();

    const int lx = tid & 31, ly = tid >> 5;
    const int x = tx0 + lx, y = ty0 + ly;
    float2 sum = f2(0.f, 0.f);

    if (x >= 3 && x < W - 3 && y >= 3 && y < H - 3) {
        const int c = (ly + 3) * TW + (lx + 3);
        const float2 cAC = sAC[c], cBD = sBD[c];
        float2 dist = f2(0.f, 0.f);
#pragma unroll
        for (int dy = 0; dy < 7; ++dy) {
            const int ro = (ly + dy) * TW + lx;
            float2 ac[7], bd[7];
#pragma unroll
            for (int dx = 0; dx < 7; ++dx) { ac[dx] = sAC[ro + dx]; }
#pragma unroll
            for (int dx = 0; dx < 7; ++dx) { bd[dx] = sBD[ro + dx]; }
#pragma unroll
            for (int dx = 0; dx < 7; ++dx) {
                // a,b: neighbor-center diffs for both losses packed
                float2 a = ac[dx] - cAC;
                float2 bb = bd[dx] - cBD;
                float2 q1 = pk_fma(a, a, f2(0.81f, 0.81f));
                float2 q2 = pk_fma(bb, bb, f2(0.81f, 0.81f));
                float2 Q  = q1 * q2;
                float2 R  = f2(__builtin_amdgcn_rsqf(Q.x), __builtin_amdgcn_rsqf(Q.y));
                float2 Pp = R * R;                 // ~= 1/Q
                float2 ab = a * bb;
                float2 S  = q1 + q2;
                float2 h  = S * Pp;
                float2 g  = pk_fma_s(-0.81f, h, f2(2.f, 2.f));
                float2 v  = ab * R;
                float2 d  = pk_fma_s(-2.f, v, g); // (t1-t2)^2
                float2 e  = pk_add_s(d, 0.1f);
                float2 r  = f2(__builtin_amdgcn_rcpf(e.x), __builtin_amdgcn_rcpf(e.y));
                dist = pk_fma(d, r, dist);        // += d/(0.1+d)
            }
        }
        const float m1 = fw_mask[(size_t)b * P + y * W + x];
        const float m2 = bw_mask[(size_t)b * P + y * W + x];
        sum.x = exp2f(0.45f * log2f(fmaf(dist.x, dist.x, 1e-6f))) * m1;
        sum.y = exp2f(0.45f * log2f(fmaf(dist.y, dist.y, 1e-6f))) * m2;
    }

#pragma unroll
    for (int off = 32; off; off >>= 1) {
        sum.x += __shfl_down(sum.x, off, 64);
        sum.y += __shfl_down(sum.y, off, 64);
    }
    __shared__ float red[8];
    const int wave = tid >> 6, lane = tid & 63;
    if (lane == 0) { red[wave] = sum.x; red[4 + wave] = sum.y; }
    __syncthreads();
    if (tid == 0) {
        float s1 = red[0] + red[1] + red[2] + red[3];
        float s2 = red[4] + red[5] + red[6] + red[7];
        atomicAdd(&out[0], s1 * (1.0f / NPIX));
        atomicAdd(&out[1], s2 * (1.0f / NPIX));
    }
}

extern "C" void kernel_launch(void* const* d_in, const int* in_sizes, int n_in,
                              void* d_out, int out_size, void* d_ws, size_t ws_size,
                              hipStream_t stream) {
    (void)in_sizes; (void)n_in; (void)out_size; (void)ws_size;
    const float* former  = (const float*)d_in[0];
    const float* latter  = (const float*)d_in[1];
    const float* flow1   = (const float*)d_in[2];
    const float* flow2   = (const float*)d_in[3];
    const float* fw_mask = (const float*)d_in[4];
    const float* bw_mask = (const float*)d_in[5];
    float* out = (float*)d_out;
    float* ws  = (float*)d_ws;
    float* gf  = ws;
    float* gl  = ws + NPIX;

    gray_kernel<<<(NPIX / 4 + 255) / 256, 256, 0, stream>>>(former, latter, gf, gl, out);
    fused_kernel<<<dim3(NBX, NBY, BB), 256, 0, stream>>>(gf, gl, flow1, flow2,
                                                         fw_mask, bw_mask, out);
}

// Round 5
// 195.026 us; speedup vs baseline: 1.0070x; 1.0070x over previous
//
#include <hip/hip_runtime.h>

#define BB 4
#define H 320
#define W 768
#define P (H*W)           // 245760
#define NPIX (BB*P)       // 983040

#define TX 32
#define TY 8
#define TW (TX+6)  // 38
#define TH (TY+6)  // 14
#define HALO (TW*TH)      // 532
#define NBX (W/TX)        // 24
#define NBY (H/TY)        // 40

typedef float v2f __attribute__((ext_vector_type(2)));

// ---------------- gray kernel (float4, + zero out) ----------------
__global__ void gray_kernel(const float* __restrict__ former,
                            const float* __restrict__ latter,
                            float* __restrict__ gf, float* __restrict__ gl,
                            float* __restrict__ out) {
    int idx = blockIdx.x * blockDim.x + threadIdx.x;
    if (idx == 0) { out[0] = 0.f; out[1] = 0.f; }
    if (idx >= NPIX / 4) return;
    int idx4 = idx * 4;
    int b = idx4 / P;
    int r = idx4 - b * P;
    const float* f = former + (size_t)b * 3 * P + r;
    const float* l = latter + (size_t)b * 3 * P + r;
    float4 fr = *(const float4*)f;
    float4 fg = *(const float4*)(f + P);
    float4 fb = *(const float4*)(f + 2 * P);
    float4 lr = *(const float4*)l;
    float4 lg = *(const float4*)(l + P);
    float4 lb = *(const float4*)(l + 2 * P);
    float4 og, ol;
    og.x = (0.299f * fr.x + 0.587f * fg.x + 0.114f * fb.x) * 255.f;
    og.y = (0.299f * fr.y + 0.587f * fg.y + 0.114f * fb.y) * 255.f;
    og.z = (0.299f * fr.z + 0.587f * fg.z + 0.114f * fb.z) * 255.f;
    og.w = (0.299f * fr.w + 0.587f * fg.w + 0.114f * fb.w) * 255.f;
    ol.x = (0.299f * lr.x + 0.587f * lg.x + 0.114f * lb.x) * 255.f;
    ol.y = (0.299f * lr.y + 0.587f * lg.y + 0.114f * lb.y) * 255.f;
    ol.z = (0.299f * lr.z + 0.587f * lg.z + 0.114f * lb.z) * 255.f;
    ol.w = (0.299f * lr.w + 0.587f * lg.w + 0.114f * lb.w) * 255.f;
    *(float4*)(gf + idx4) = og;
    *(float4*)(gl + idx4) = ol;
}

__device__ __forceinline__ float bilinear(const float* __restrict__ img, float fx, float fy) {
    float x0 = floorf(fx), y0 = floorf(fy);
    float wx = fx - x0, wy = fy - y0;
    float x0c = fminf(fmaxf(x0,       0.f), (float)(W - 1));
    float x1c = fminf(fmaxf(x0 + 1.f, 0.f), (float)(W - 1));
    float y0c = fminf(fmaxf(y0,       0.f), (float)(H - 1));
    float y1c = fminf(fmaxf(y0 + 1.f, 0.f), (float)(H - 1));
    int x0i = (int)x0c, x1i = (int)x1c, y0i = (int)y0c, y1i = (int)y1c;
    float Ia = img[y0i * W + x0i], Ib = img[y0i * W + x1i];
    float Ic = img[y1i * W + x0i], Id = img[y1i * W + x1i];
    float omx = 1.f - wx, omy = 1.f - wy;
    return Ia * omx * omy + Ib * wx * omy + Ic * omx * wy + Id * wx * wy;
}

// ---------------- fused warp + census + distance + charbonnier ----------------
__global__ __launch_bounds__(256)
void fused_kernel(const float* __restrict__ gf, const float* __restrict__ gl,
                  const float* __restrict__ flow1, const float* __restrict__ flow2,
                  const float* __restrict__ fw_mask, const float* __restrict__ bw_mask,
                  float* __restrict__ out) {
    __shared__ v2f sAC[HALO];  // {former-gray, latter-gray}
    __shared__ v2f sBD[HALO];  // {warp(latter,f1), warp(former,f2)}
    const int b   = blockIdx.z;
    const int tx0 = blockIdx.x * TX;
    const int ty0 = blockIdx.y * TY;
    const int tid = threadIdx.x;

    const float* pGF = gf + (size_t)b * P;
    const float* pGL = gl + (size_t)b * P;
    const float* pF1 = flow1 + (size_t)b * 2 * P;
    const float* pF2 = flow2 + (size_t)b * 2 * P;

    for (int i = tid; i < HALO; i += 256) {
        int ly = i / TW, lx = i - ly * TW;
        int gx = min(max(tx0 - 3 + lx, 0), W - 1);
        int gy = min(max(ty0 - 3 + ly, 0), H - 1);
        int o = gy * W + gx;
        float u1 = pF1[o], v1 = pF1[P + o];
        float u2 = pF2[o], v2 = pF2[P + o];
        v2f ac, bd;
        ac.x = pGF[o];
        ac.y = pGL[o];
        bd.x = bilinear(pGL, (float)gx + u1, (float)gy + v1);
        bd.y = bilinear(pGF, (float)gx + u2, (float)gy + v2);
        sAC[i] = ac;
        sBD[i] = bd;
    }
    __syncthreads();

    const int lx = tid & 31, ly = tid >> 5;
    const int x = tx0 + lx, y = ty0 + ly;
    v2f sum = {0.f, 0.f};

    if (x >= 3 && x < W - 3 && y >= 3 && y < H - 3) {
        const v2f C081 = {0.81f, 0.81f};
        const v2f C01  = {0.1f, 0.1f};
        const v2f Cm1  = {-1.f, -1.f};
        const int c = (ly + 3) * TW + (lx + 3);
        const v2f nAC = Cm1 * sAC[c];   // -center (ref)
        const v2f nBD = Cm1 * sBD[c];   // -center (est)
        v2f dist = {0.f, 0.f};
#pragma unroll
        for (int dy = 0; dy < 7; ++dy) {
            const int ro = (ly + dy) * TW + lx;
            v2f ac[7], bd[7];
#pragma unroll
            for (int dx = 0; dx < 7; ++dx) { ac[dx] = sAC[ro + dx]; }
#pragma unroll
            for (int dx = 0; dx < 7; ++dx) { bd[dx] = sBD[ro + dx]; }
#pragma unroll
            for (int dx = 0; dx < 7; ++dx) {
                v2f t1 = ac[dx] + nAC;                         // pk_add
                v2f t2 = bd[dx] + nBD;                         // pk_add
                v2f q1 = __builtin_elementwise_fma(t1, t1, C081);
                v2f q2 = __builtin_elementwise_fma(t2, t2, C081);
                v2f r1, r2;
                r1.x = __builtin_amdgcn_rsqf(q1.x);
                r1.y = __builtin_amdgcn_rsqf(q1.y);
                r2.x = __builtin_amdgcn_rsqf(q2.x);
                r2.y = __builtin_amdgcn_rsqf(q2.y);
                t1 = t1 * r1;                                  // pk_mul
                t2 = t2 * r2;                                  // pk_mul
                v2f d = __builtin_elementwise_fma(t2, Cm1, t1); // t1 - t2
                d = d * d;                                     // pk_mul
                v2f e = d + C01;                               // pk_add
                v2f rc;
                rc.x = __builtin_amdgcn_rcpf(e.x);
                rc.y = __builtin_amdgcn_rcpf(e.y);
                dist = __builtin_elementwise_fma(d, rc, dist); // pk_fma
            }
        }
        const float m1 = fw_mask[(size_t)b * P + y * W + x];
        const float m2 = bw_mask[(size_t)b * P + y * W + x];
        sum.x = exp2f(0.45f * log2f(fmaf(dist.x, dist.x, 1e-6f))) * m1;
        sum.y = exp2f(0.45f * log2f(fmaf(dist.y, dist.y, 1e-6f))) * m2;
    }

#pragma unroll
    for (int off = 32; off; off >>= 1) {
        sum.x += __shfl_down(sum.x, off, 64);
        sum.y += __shfl_down(sum.y, off, 64);
    }
    __shared__ float red[8];
    const int wave = tid >> 6, lane = tid & 63;
    if (lane == 0) { red[wave] = sum.x; red[4 + wave] = sum.y; }
    __syncthreads();
    if (tid == 0) {
        float s1 = red[0] + red[1] + red[2] + red[3];
        float s2 = red[4] + red[5] + red[6] + red[7];
        atomicAdd(&out[0], s1 * (1.0f / NPIX));
        atomicAdd(&out[1], s2 * (1.0f / NPIX));
    }
}

extern "C" void kernel_launch(void* const* d_in, const int* in_sizes, int n_in,
                              void* d_out, int out_size, void* d_ws, size_t ws_size,
                              hipStream_t stream) {
    (void)in_sizes; (void)n_in; (void)out_size; (void)ws_size;
    const float* former  = (const float*)d_in[0];
    const float* latter  = (const float*)d_in[1];
    const float* flow1   = (const float*)d_in[2];
    const float* flow2   = (const float*)d_in[3];
    const float* fw_mask = (const float*)d_in[4];
    const float* bw_mask = (const float*)d_in[5];
    float* out = (float*)d_out;
    float* ws  = (float*)d_ws;
    float* gf  = ws;
    float* gl  = ws + NPIX;

    gray_kernel<<<(NPIX / 4 + 255) / 256, 256, 0, stream>>>(former, latter, gf, gl, out);
    fused_kernel<<<dim3(NBX, NBY, BB), 256, 0, stream>>>(gf, gl, flow1, flow2,
                                                         fw_mask, bw_mask, out);
}

// Round 6
// 194.532 us; speedup vs baseline: 1.0095x; 1.0025x over previous
//
#include <hip/hip_runtime.h>

#define BB 4
#define H 320
#define W 768
#define P (H*W)           // 245760
#define NPIX (BB*P)       // 983040

#define TX 32
#define TY 8
#define TW (TX+6)  // 38
#define TH (TY+6)  // 14
#define HALO (TW*TH)      // 532
#define NBX (W/TX)        // 24
#define NBY (H/TY)        // 40

// ---------------- gray kernel (float4, + zero out) ----------------
__global__ void gray_kernel(const float* __restrict__ former,
                            const float* __restrict__ latter,
                            float* __restrict__ gf, float* __restrict__ gl,
                            float* __restrict__ out) {
    int idx = blockIdx.x * blockDim.x + threadIdx.x;
    if (idx == 0) { out[0] = 0.f; out[1] = 0.f; }
    if (idx >= NPIX / 4) return;
    int idx4 = idx * 4;
    int b = idx4 / P;
    int r = idx4 - b * P;
    const float* f = former + (size_t)b * 3 * P + r;
    const float* l = latter + (size_t)b * 3 * P + r;
    float4 fr = *(const float4*)f;
    float4 fg = *(const float4*)(f + P);
    float4 fb = *(const float4*)(f + 2 * P);
    float4 lr = *(const float4*)l;
    float4 lg = *(const float4*)(l + P);
    float4 lb = *(const float4*)(l + 2 * P);
    float4 og, ol;
    og.x = (0.299f * fr.x + 0.587f * fg.x + 0.114f * fb.x) * 255.f;
    og.y = (0.299f * fr.y + 0.587f * fg.y + 0.114f * fb.y) * 255.f;
    og.z = (0.299f * fr.z + 0.587f * fg.z + 0.114f * fb.z) * 255.f;
    og.w = (0.299f * fr.w + 0.587f * fg.w + 0.114f * fb.w) * 255.f;
    ol.x = (0.299f * lr.x + 0.587f * lg.x + 0.114f * lb.x) * 255.f;
    ol.y = (0.299f * lr.y + 0.587f * lg.y + 0.114f * lb.y) * 255.f;
    ol.z = (0.299f * lr.z + 0.587f * lg.z + 0.114f * lb.z) * 255.f;
    ol.w = (0.299f * lr.w + 0.587f * lg.w + 0.114f * lb.w) * 255.f;
    *(float4*)(gf + idx4) = og;
    *(float4*)(gl + idx4) = ol;
}

__device__ __forceinline__ float bilinear(const float* __restrict__ img, float fx, float fy) {
    float x0 = floorf(fx), y0 = floorf(fy);
    float wx = fx - x0, wy = fy - y0;
    float x0c = fminf(fmaxf(x0,       0.f), (float)(W - 1));
    float x1c = fminf(fmaxf(x0 + 1.f, 0.f), (float)(W - 1));
    float y0c = fminf(fmaxf(y0,       0.f), (float)(H - 1));
    float y1c = fminf(fmaxf(y0 + 1.f, 0.f), (float)(H - 1));
    int x0i = (int)x0c, x1i = (int)x1c, y0i = (int)y0c, y1i = (int)y1c;
    float Ia = img[y0i * W + x0i], Ib = img[y0i * W + x1i];
    float Ic = img[y1i * W + x0i], Id = img[y1i * W + x1i];
    float omx = 1.f - wx, omy = 1.f - wy;
    return Ia * omx * omy + Ib * wx * omy + Ic * omx * wy + Id * wx * wy;
}

// ---------------- fused warp + census + distance + charbonnier ----------------
// NOTE: scalar f32, 4 separate LDS arrays, per-row register batching.
// This exact shape measured 56 us / VALUBusy 79% (round 2). Vector-typed
// (float2/v2f) variants scalarize AND break load batching: 110-113 us.
__global__ __launch_bounds__(256)
void fused_kernel(const float* __restrict__ gf, const float* __restrict__ gw_unused,
                  const float* __restrict__ gl,
                  const float* __restrict__ flow1, const float* __restrict__ flow2,
                  const float* __restrict__ fw_mask, const float* __restrict__ bw_mask,
                  float* __restrict__ out) {
    __shared__ float sA[HALO], sB[HALO], sC[HALO], sD[HALO];
    const int b   = blockIdx.z;
    const int tx0 = blockIdx.x * TX;
    const int ty0 = blockIdx.y * TY;
    const int tid = threadIdx.x;

    const float* pGF = gf + (size_t)b * P;
    const float* pGL = gl + (size_t)b * P;
    const float* pF1 = flow1 + (size_t)b * 2 * P;
    const float* pF2 = flow2 + (size_t)b * 2 * P;

    for (int i = tid; i < HALO; i += 256) {
        int ly = i / TW, lx = i - ly * TW;
        int gx = min(max(tx0 - 3 + lx, 0), W - 1);
        int gy = min(max(ty0 - 3 + ly, 0), H - 1);
        int o = gy * W + gx;
        sA[i] = pGF[o];
        sC[i] = pGL[o];
        float u1 = pF1[o], v1 = pF1[P + o];
        float u2 = pF2[o], v2 = pF2[P + o];
        sB[i] = bilinear(pGL, (float)gx + u1, (float)gy + v1);
        sD[i] = bilinear(pGF, (float)gx + u2, (float)gy + v2);
    }
    __syncthreads();

    const int lx = tid & 31, ly = tid >> 5;
    const int x = tx0 + lx, y = ty0 + ly;
    float sum1 = 0.f, sum2 = 0.f;

    if (x >= 3 && x < W - 3 && y >= 3 && y < H - 3) {
        const int c = (ly + 3) * TW + (lx + 3);
        const float c1 = sA[c], c2 = sB[c], c3 = sC[c], c4 = sD[c];
        float dist1 = 0.f, dist2 = 0.f;
#pragma unroll
        for (int dy = 0; dy < 7; ++dy) {
            const int ro = (ly + dy) * TW + lx;
            float a[7], bv[7], cv[7], dv[7];
#pragma unroll
            for (int dx = 0; dx < 7; ++dx) { a[dx] = sA[ro + dx]; bv[dx] = sB[ro + dx]; }
#pragma unroll
            for (int dx = 0; dx < 7; ++dx) { cv[dx] = sC[ro + dx]; dv[dx] = sD[ro + dx]; }
#pragma unroll
            for (int dx = 0; dx < 7; ++dx) {
                if (dy == 3 && dx == 3) continue;   // center term is exactly 0
                float t1 = a[dx] - c1;
                float t2 = bv[dx] - c2;
                t1 *= __builtin_amdgcn_rsqf(0.81f + t1 * t1);
                t2 *= __builtin_amdgcn_rsqf(0.81f + t2 * t2);
                float d = t1 - t2; d *= d;
                dist1 += d * __builtin_amdgcn_rcpf(0.1f + d);
            }
#pragma unroll
            for (int dx = 0; dx < 7; ++dx) {
                if (dy == 3 && dx == 3) continue;   // center term is exactly 0
                float t3 = cv[dx] - c3;
                float t4 = dv[dx] - c4;
                t3 *= __builtin_amdgcn_rsqf(0.81f + t3 * t3);
                t4 *= __builtin_amdgcn_rsqf(0.81f + t4 * t4);
                float d = t3 - t4; d *= d;
                dist2 += d * __builtin_amdgcn_rcpf(0.1f + d);
            }
        }
        const float m1 = fw_mask[(size_t)b * P + y * W + x];
        const float m2 = bw_mask[(size_t)b * P + y * W + x];
        sum1 = exp2f(0.45f * log2f(fmaf(dist1, dist1, 1e-6f))) * m1;
        sum2 = exp2f(0.45f * log2f(fmaf(dist2, dist2, 1e-6f))) * m2;
    }

#pragma unroll
    for (int off = 32; off; off >>= 1) {
        sum1 += __shfl_down(sum1, off, 64);
        sum2 += __shfl_down(sum2, off, 64);
    }
    __shared__ float red[8];
    const int wave = tid >> 6, lane = tid & 63;
    if (lane == 0) { red[wave] = sum1; red[4 + wave] = sum2; }
    __syncthreads();
    if (tid == 0) {
        float s1 = red[0] + red[1] + red[2] + red[3];
        float s2 = red[4] + red[5] + red[6] + red[7];
        atomicAdd(&out[0], s1 * (1.0f / NPIX));
        atomicAdd(&out[1], s2 * (1.0f / NPIX));
    }
}

extern "C" void kernel_launch(void* const* d_in, const int* in_sizes, int n_in,
                              void* d_out, int out_size, void* d_ws, size_t ws_size,
                              hipStream_t stream) {
    (void)in_sizes; (void)n_in; (void)out_size; (void)ws_size;
    const float* former  = (const float*)d_in[0];
    const float* latter  = (const float*)d_in[1];
    const float* flow1   = (const float*)d_in[2];
    const float* flow2   = (const float*)d_in[3];
    const float* fw_mask = (const float*)d_in[4];
    const float* bw_mask = (const float*)d_in[5];
    float* out = (float*)d_out;
    float* ws  = (float*)d_ws;
    float* gf  = ws;
    float* gl  = ws + NPIX;

    gray_kernel<<<(NPIX / 4 + 255) / 256, 256, 0, stream>>>(former, latter, gf, gl, out);
    fused_kernel<<<dim3(NBX, NBY, BB), 256, 0, stream>>>(gf, nullptr, gl, flow1, flow2,
                                                         fw_mask, bw_mask, out);
}

// Round 7
// 140.334 us; speedup vs baseline: 1.3994x; 1.3862x over previous
//
#include <hip/hip_runtime.h>

#define BB 4
#define H 320
#define W 768
#define P (H*W)           // 245760
#define NPIX (BB*P)       // 983040

#define TX 32
#define TY 8
#define TW (TX+6)  // 38
#define TH (TY+6)  // 14
#define HALO (TW*TH)      // 532
#define NBX (W/TX)        // 24
#define NBY (H/TY)        // 40
#define NBLK (NBX*NBY*BB) // 3840

// ---------------- gray kernel (float4) ----------------
__global__ void gray_kernel(const float* __restrict__ former,
                            const float* __restrict__ latter,
                            float* __restrict__ gf, float* __restrict__ gl) {
    int idx = blockIdx.x * blockDim.x + threadIdx.x;
    if (idx >= NPIX / 4) return;
    int idx4 = idx * 4;
    int b = idx4 / P;
    int r = idx4 - b * P;
    const float* f = former + (size_t)b * 3 * P + r;
    const float* l = latter + (size_t)b * 3 * P + r;
    float4 fr = *(const float4*)f;
    float4 fg = *(const float4*)(f + P);
    float4 fb = *(const float4*)(f + 2 * P);
    float4 lr = *(const float4*)l;
    float4 lg = *(const float4*)(l + P);
    float4 lb = *(const float4*)(l + 2 * P);
    float4 og, ol;
    og.x = (0.299f * fr.x + 0.587f * fg.x + 0.114f * fb.x) * 255.f;
    og.y = (0.299f * fr.y + 0.587f * fg.y + 0.114f * fb.y) * 255.f;
    og.z = (0.299f * fr.z + 0.587f * fg.z + 0.114f * fb.z) * 255.f;
    og.w = (0.299f * fr.w + 0.587f * fg.w + 0.114f * fb.w) * 255.f;
    ol.x = (0.299f * lr.x + 0.587f * lg.x + 0.114f * lb.x) * 255.f;
    ol.y = (0.299f * lr.y + 0.587f * lg.y + 0.114f * lb.y) * 255.f;
    ol.z = (0.299f * lr.z + 0.587f * lg.z + 0.114f * lb.z) * 255.f;
    ol.w = (0.299f * lr.w + 0.587f * lg.w + 0.114f * lb.w) * 255.f;
    *(float4*)(gf + idx4) = og;
    *(float4*)(gl + idx4) = ol;
}

__device__ __forceinline__ float bilinear(const float* __restrict__ img, float fx, float fy) {
    float x0 = floorf(fx), y0 = floorf(fy);
    float wx = fx - x0, wy = fy - y0;
    float x0c = fminf(fmaxf(x0,       0.f), (float)(W - 1));
    float x1c = fminf(fmaxf(x0 + 1.f, 0.f), (float)(W - 1));
    float y0c = fminf(fmaxf(y0,       0.f), (float)(H - 1));
    float y1c = fminf(fmaxf(y0 + 1.f, 0.f), (float)(H - 1));
    int x0i = (int)x0c, x1i = (int)x1c, y0i = (int)y0c, y1i = (int)y1c;
    float Ia = img[y0i * W + x0i], Ib = img[y0i * W + x1i];
    float Ic = img[y1i * W + x0i], Id = img[y1i * W + x1i];
    float omx = 1.f - wx, omy = 1.f - wy;
    return Ia * omx * omy + Ib * wx * omy + Ic * omx * wy + Id * wx * wy;
}

// ---------------- fused warp + census + distance + charbonnier ----------------
// NOTE (journal): scalar f32, 4 separate LDS arrays, per-row register batching.
// TAIL MUST BE per-block plain stores + separate reduce. 3840 blocks x 2
// atomicAdds to one cache line serialize at ~68 atomics/us => ~110 us kernel
// floor (measured rounds 1/3/5/6); partials tail measured 56 us (round 2).
__global__ __launch_bounds__(256)
void fused_kernel(const float* __restrict__ gf, const float* __restrict__ gl,
                  const float* __restrict__ flow1, const float* __restrict__ flow2,
                  const float* __restrict__ fw_mask, const float* __restrict__ bw_mask,
                  float* __restrict__ partials) {
    __shared__ float sA[HALO], sB[HALO], sC[HALO], sD[HALO];
    const int b   = blockIdx.z;
    const int tx0 = blockIdx.x * TX;
    const int ty0 = blockIdx.y * TY;
    const int tid = threadIdx.x;

    const float* pGF = gf + (size_t)b * P;
    const float* pGL = gl + (size_t)b * P;
    const float* pF1 = flow1 + (size_t)b * 2 * P;
    const float* pF2 = flow2 + (size_t)b * 2 * P;

    for (int i = tid; i < HALO; i += 256) {
        int ly = i / TW, lx = i - ly * TW;
        int gx = min(max(tx0 - 3 + lx, 0), W - 1);
        int gy = min(max(ty0 - 3 + ly, 0), H - 1);
        int o = gy * W + gx;
        sA[i] = pGF[o];
        sC[i] = pGL[o];
        float u1 = pF1[o], v1 = pF1[P + o];
        float u2 = pF2[o], v2 = pF2[P + o];
        sB[i] = bilinear(pGL, (float)gx + u1, (float)gy + v1);
        sD[i] = bilinear(pGF, (float)gx + u2, (float)gy + v2);
    }
    __syncthreads();

    const int lx = tid & 31, ly = tid >> 5;
    const int x = tx0 + lx, y = ty0 + ly;
    float sum1 = 0.f, sum2 = 0.f;

    if (x >= 3 && x < W - 3 && y >= 3 && y < H - 3) {
        const int c = (ly + 3) * TW + (lx + 3);
        const float c1 = sA[c], c2 = sB[c], c3 = sC[c], c4 = sD[c];
        float dist1 = 0.f, dist2 = 0.f;
#pragma unroll
        for (int dy = 0; dy < 7; ++dy) {
            const int ro = (ly + dy) * TW + lx;
            float a[7], bv[7], cv[7], dv[7];
#pragma unroll
            for (int dx = 0; dx < 7; ++dx) { a[dx] = sA[ro + dx]; bv[dx] = sB[ro + dx]; }
#pragma unroll
            for (int dx = 0; dx < 7; ++dx) { cv[dx] = sC[ro + dx]; dv[dx] = sD[ro + dx]; }
#pragma unroll
            for (int dx = 0; dx < 7; ++dx) {
                if (dy == 3 && dx == 3) continue;   // center term is exactly 0
                float t1 = a[dx] - c1;
                float t2 = bv[dx] - c2;
                t1 *= __builtin_amdgcn_rsqf(0.81f + t1 * t1);
                t2 *= __builtin_amdgcn_rsqf(0.81f + t2 * t2);
                float d = t1 - t2; d *= d;
                dist1 += d * __builtin_amdgcn_rcpf(0.1f + d);
            }
#pragma unroll
            for (int dx = 0; dx < 7; ++dx) {
                if (dy == 3 && dx == 3) continue;   // center term is exactly 0
                float t3 = cv[dx] - c3;
                float t4 = dv[dx] - c4;
                t3 *= __builtin_amdgcn_rsqf(0.81f + t3 * t3);
                t4 *= __builtin_amdgcn_rsqf(0.81f + t4 * t4);
                float d = t3 - t4; d *= d;
                dist2 += d * __builtin_amdgcn_rcpf(0.1f + d);
            }
        }
        const float m1 = fw_mask[(size_t)b * P + y * W + x];
        const float m2 = bw_mask[(size_t)b * P + y * W + x];
        sum1 = exp2f(0.45f * log2f(fmaf(dist1, dist1, 1e-6f))) * m1;
        sum2 = exp2f(0.45f * log2f(fmaf(dist2, dist2, 1e-6f))) * m2;
    }

#pragma unroll
    for (int off = 32; off; off >>= 1) {
        sum1 += __shfl_down(sum1, off, 64);
        sum2 += __shfl_down(sum2, off, 64);
    }
    __shared__ float red[8];
    const int wave = tid >> 6, lane = tid & 63;
    if (lane == 0) { red[wave] = sum1; red[4 + wave] = sum2; }
    __syncthreads();
    if (tid == 0) {
        const int blk = (blockIdx.z * NBY + blockIdx.y) * NBX + blockIdx.x;
        partials[2 * blk]     = red[0] + red[1] + red[2] + red[3];
        partials[2 * blk + 1] = red[4] + red[5] + red[6] + red[7];
    }
}

// ---------------- final reduce ----------------
__global__ __launch_bounds__(256)
void reduce_kernel(const float* __restrict__ partials, float* __restrict__ out) {
    const int tid = threadIdx.x;
    float s1 = 0.f, s2 = 0.f;
    for (int i = tid; i < NBLK; i += 256) {
        s1 += partials[2 * i];
        s2 += partials[2 * i + 1];
    }
#pragma unroll
    for (int off = 32; off; off >>= 1) {
        s1 += __shfl_down(s1, off, 64);
        s2 += __shfl_down(s2, off, 64);
    }
    __shared__ float red[8];
    const int wave = tid >> 6, lane = tid & 63;
    if (lane == 0) { red[wave] = s1; red[4 + wave] = s2; }
    __syncthreads();
    if (tid == 0) {
        out[0] = (red[0] + red[1] + red[2] + red[3]) * (1.0f / NPIX);
        out[1] = (red[4] + red[5] + red[6] + red[7]) * (1.0f / NPIX);
    }
}

extern "C" void kernel_launch(void* const* d_in, const int* in_sizes, int n_in,
                              void* d_out, int out_size, void* d_ws, size_t ws_size,
                              hipStream_t stream) {
    (void)in_sizes; (void)n_in; (void)out_size; (void)ws_size;
    const float* former  = (const float*)d_in[0];
    const float* latter  = (const float*)d_in[1];
    const float* flow1   = (const float*)d_in[2];
    const float* flow2   = (const float*)d_in[3];
    const float* fw_mask = (const float*)d_in[4];
    const float* bw_mask = (const float*)d_in[5];
    float* out = (float*)d_out;
    float* ws  = (float*)d_ws;
    float* gf       = ws;
    float* gl       = ws + NPIX;
    float* partials = ws + 2 * (size_t)NPIX;

    gray_kernel<<<(NPIX / 4 + 255) / 256, 256, 0, stream>>>(former, latter, gf, gl);
    fused_kernel<<<dim3(NBX, NBY, BB), 256, 0, stream>>>(gf, gl, flow1, flow2,
                                                         fw_mask, bw_mask, partials);
    reduce_kernel<<<1, 256, 0, stream>>>(partials, out);
}